// Round 12
// baseline (181.989 us; speedup 1.0000x reference)
//
#include <hip/hip_runtime.h>
#include <stdint.h>

typedef unsigned short u16;
typedef __attribute__((ext_vector_type(8))) short short8;
typedef __attribute__((ext_vector_type(4))) float floatx4;

#define NB 32
#define NC 256
#define NH 32
#define NW 32
#define NO 256
#define NPIX (NH*NW)     // 1024
#define KPIX 9
#define NG 9             // subarrays (groups)
#define RUN 32           // padded run length (per kernel-tap within group)
#define GK (NG*RUN)      // 288 k-slots per group
#define KTOT (NG*GK)     // 2592 k-slots
#define PADH 34
#define PADSP (PADH*PADH)       // 1156
#define QA_BSTRIDE (PADSP*NC)   // 295936 elems per batch

#define AS1 __attribute__((address_space(1)))
#define AS3 __attribute__((address_space(3)))

// ---------------- fused: absmax (atomicMax, single scalar) + zero qa halo borders ----------------
// pmax[0] = absmax(x) bits, pmax[1] = absmax(w) bits. Non-negative floats: uint
// bit-pattern order == float order, so atomicMax yields the bitwise-identical max.
// pmax[0..1] zeroed by an 8-byte hipMemsetAsync before this kernel.
__global__ void fused_pre(const float4* __restrict__ x4, int nx4,
                          const float4* __restrict__ w4, int nw4,
                          float* __restrict__ pmax, u16* __restrict__ qa) {
  int bid = blockIdx.x;
  if (bid >= 1088) {
    int zb = bid - 1088;              // 9 blocks per batch
    int b = zb / 9;
    int rem = (zb % 9) * 256 + threadIdx.x;   // need <2112 (132 px * 16 ch-groups)
    if (rem >= 2112) return;
    int pb = rem >> 4, c16 = rem & 15;
    int y, x;
    if (pb < 68) { y = (pb >= 34) ? 33 : 0; x = pb % 34; }
    else { int q = pb - 68; y = 1 + (q >> 1); x = (q & 1) ? 33 : 0; }
    uint4 z; z.x = z.y = z.z = z.w = 0u;
    *(uint4*)(qa + ((size_t)(b * PADH + y) * PADH + x) * NC + c16 * 16) = z;
    return;
  }
  const float4* p; int n4; int nb, b0; int slot;
  if (bid < 1024) { p = x4; n4 = nx4; nb = 1024; b0 = bid; slot = 0; }
  else            { p = w4; n4 = nw4; nb = 64;   b0 = bid - 1024; slot = 1; }
  float m = 0.f;
  for (int i = b0 * blockDim.x + threadIdx.x; i < n4; i += nb * blockDim.x) {
    float4 v = p[i];
    m = fmaxf(m, fmaxf(fmaxf(fabsf(v.x), fabsf(v.y)), fmaxf(fabsf(v.z), fabsf(v.w))));
  }
#pragma unroll
  for (int off = 32; off > 0; off >>= 1)
    m = fmaxf(m, __shfl_down(m, off, 64));
  __shared__ float sm[4];
  int lane = threadIdx.x & 63, wv = threadIdx.x >> 6;
  if (lane == 0) sm[wv] = m;
  __syncthreads();
  if (threadIdx.x == 0) {
    m = fmaxf(fmaxf(sm[0], sm[1]), fmaxf(sm[2], sm[3]));
    atomicMax((unsigned int*)pmax + slot, __float_as_uint(m));
  }
}

// ---------------- fused quantization: acts + weights ----------------
// Weight packing (from R4): slot j of (g,r) maps to channel cw(g)+j with
// cw = (256g/9)&~3 UNIFORM across the group's 9 taps (verified subset property).
// mx/mw come from pmax[0]/pmax[1] directly (no per-block re-reduction).
__global__ void fused_quant(const float* __restrict__ x, const float* __restrict__ w,
                            const float* __restrict__ pmax,
                            u16* __restrict__ qa, u16* __restrict__ wq,
                            float* __restrict__ lossp) {
  float mx = pmax[0], mw = pmax[1];
  int bid = blockIdx.x, tid = threadIdx.x;
  if (bid < 1024) {
    __shared__ u16 ts[32][264];        // [x][c], row stride 264 (16B-aligned rows)
    double s = (double)mx + 1e-12;
    double inv = 255.0 / s;
    int b = bid >> 5, y = bid & 31;
    const float4* x4 = (const float4*)x;
    int xc = tid & 7, crow = tid >> 3;
#pragma unroll
    for (int it = 0; it < 8; it++) {
      int c = crow + 32 * it;
      float4 v = x4[((size_t)(b * NC + c) * NH + y) * 8 + xc];
      float q0 = (float)rint((double)v.x * inv);
      float q1 = (float)rint((double)v.y * inv);
      float q2 = (float)rint((double)v.z * inv);
      float q3 = (float)rint((double)v.w * inv);
      ts[xc * 4 + 0][c] = (u16)(__float_as_uint(q0) >> 16);
      ts[xc * 4 + 1][c] = (u16)(__float_as_uint(q1) >> 16);
      ts[xc * 4 + 2][c] = (u16)(__float_as_uint(q2) >> 16);
      ts[xc * 4 + 3][c] = (u16)(__float_as_uint(q3) >> 16);
    }
    __syncthreads();
    int xx = tid >> 3, qwl = tid & 7;
    u16* orow = qa + ((size_t)(b * PADH + y + 1) * PADH + (xx + 1)) * NC;
#pragma unroll
    for (int it = 0; it < 4; it++) {
      int qw = qwl + 8 * it;
      *(uint4*)(orow + qw * 8) = *(const uint4*)&ts[xx][qw * 8];
    }
    return;
  }
  // ---- weights: 2592 blocks cover NO*KTOT = 663552 slots exactly ----
  double s = (double)mw + 1e-12;
  double inv = 15.0 / s;
  int idx = (bid - 1024) * 256 + tid;
  if (idx == 0) *lossp = 0.0f;                  // a_loss output
  int o = idx / KTOT, kk = idx % KTOT;
  int g = kk / GK, rem = kk % GK;
  int r = rem / RUN, j = rem % RUN;
  int clo = (256 * g - r + 8) / 9;
  int chi = (256 * (g + 1) - r + 8) / 9; if (chi > NC) chi = NC;
  int cst = ((256 * g) / 9) & ~3;               // UNIFORM per-group window start
  int c = cst + j;
  float val = 0.f;
  if (c >= clo && c < chi) {
    float wv = w[((size_t)o * NC + c) * KPIX + r];
    val = (float)rint((double)wv * inv);
  }
  wq[idx] = (u16)(__float_as_uint(val) >> 16);
}

// ---------------- fused GEMM + per-group ADC ----------------
// Champion R10 frame (128x128 tile, grid (256,2) = 2 blocks/CU, 8 waves of 64x32,
// conflict-free rotated slab, lane-constant addrA[4][9], f64 ADC fold, atomicMax
// scalar pmax) with ONE structural delta: lB DOUBLE-BUFFERED (sA single), cutting
// barriers 54 -> 35 (27 chunk barriers + 8 group-end slab-WAR barriers). The WAR
// barrier after compute is unneeded for B (stage writes the OTHER buffer, whose
// reads closed at the previous barrier). Stage position unchanged (after compute,
// R6/R10-proven; R1/R5/R11 all showed issue-early regresses here). LDS total
// 49152 + 13056 = 62.2 KB -- the R11 lesson: >=75 KB/block silently drops to
// 1 block/CU (occ 19-21% across R3/R5/R11); 62 KB keeps the 2-block overlap the
// drain frame depends on. launch_bounds(512,2): parity state adds ~4 regs; a
// 64-cap would risk an R7-style spill; grid supplies only 2 blocks/CU anyway.
// Numerics: identical MFMA order + f64 fold -> bitwise-identical output.
__global__ __launch_bounds__(512, 2) void gemm_adc(const u16* __restrict__ qa,
                                                   const u16* __restrict__ wq,
                                                   const float* __restrict__ pmax,
                                                   float* __restrict__ out) {
  __shared__ __align__(16) u16 lB[24576];     // 49152 B: 2 bufs x (3 runs x 128 x 32)
  __shared__ __align__(16) u16 sA[6528];      // 13056 B: 204 px x 32 ch (rotated)
  const int tid = threadIdx.x;
  float mx = pmax[0], mw = pmax[1];

  const int mblk = blockIdx.x, nblk = blockIdx.y;
  const int b = mblk >> 3;
  const int p0 = (mblk & 7) * 128;        // pixel base (4 image rows of 32)
  const int y0 = (mblk & 7) * 4;          // slab top row in padded coords
  const int n0 = nblk * 128;
  const int lane = tid & 63, wv = tid >> 6;
  const int wm = (wv & 1) * 64, wn = (wv >> 1) * 32;
  const int fm = lane & 15, fq = lane >> 4;
  const int swz = (fq + ((fm >> 1) & 3)) & 3;

  double sa = (double)mx + 1e-12;
  double sw = (double)mw + 1e-12;
  double Sstep = sa * sw * 0.999 / 459.0;   // I/step = intsum * Sstep

  // ---- precompute all 36 A-fragment LDS addresses (u16 units), lane-constant ----
  const int OFS[9] = {0, 1, 2, 34, 35, 36, 68, 69, 70};   // rc*34 + ri
  int addrA[4][9];
#pragma unroll
  for (int mi = 0; mi < 4; mi++) {
    int pr = wm + mi * 16 + fm;
    int pixb = (pr >> 5) * 34 + (pr & 31);
#pragma unroll
    for (int t = 0; t < 9; t++) {
      int P = pixb + OFS[t];
      addrA[mi][t] = P * 32 + (((fq + ((P >> 1) & 3)) & 3) << 3);
    }
  }
  // B read offsets (lane-constant)
  int bno[2];
#pragma unroll
  for (int ni = 0; ni < 2; ni++) bno[ni] = (wn + ni * 16 + fm) * RUN + swz * 8;

  // B staging geometry: 3 loads/thread, slot s = i*512 + tid (i = run index)
  // row = tid>>2, word = tid&3, jsrc = ((tid&3)-((tid>>3)&3))&3 (same swizzle)
  const int jsrc = ((tid & 3) - ((tid >> 3) & 3)) & 3;
  const u16* Bb = wq + (size_t)(n0 + (tid >> 2)) * KTOT + jsrc * 8;

  // slab staging geometry: 816 slots; i0: s=tid (all), i1: s=512+tid (tid<304)
  const u16* Abase = qa + (size_t)b * QA_BSTRIDE + (size_t)y0 * PADH * NC;
  int soff[2], sdst[2];
#pragma unroll
  for (int i = 0; i < 2; i++) {
    int s = i * 512 + tid;
    soff[i] = (s >> 2) * NC + ((((s & 3) - ((s >> 3) & 3)) & 3) << 3);
    sdst[i] = s * 8;
  }

  floatx4 acc[4][2];
  float tot[4][2][4];
#pragma unroll
  for (int mi = 0; mi < 4; mi++)
#pragma unroll
    for (int ni = 0; ni < 2; ni++)
#pragma unroll
      for (int rr = 0; rr < 4; rr++) { acc[mi][ni][rr] = 0.f; tot[mi][ni][rr] = 0.f; }

  auto STAGE_SLAB = [&](int gp) {
    int cw = ((256 * gp) / 9) & ~3;
    const u16* srcg = Abase + cw;
    __builtin_amdgcn_global_load_lds((const AS1 void*)(srcg + soff[0]),
                                     (AS3 void*)&sA[sdst[0]], 16, 0, 0);
    if (tid < 304)
      __builtin_amdgcn_global_load_lds((const AS1 void*)(srcg + soff[1]),
                                       (AS3 void*)&sA[sdst[1]], 16, 0, 0);
  };
  auto STAGE_B = [&](int kb0, int bbn) {
#pragma unroll
    for (int i = 0; i < 3; i++)
      __builtin_amdgcn_global_load_lds((const AS1 void*)(Bb + kb0 + i * RUN),
                                       (AS3 void*)&lB[bbn + (i * 512 + tid) * 8], 16, 0, 0);
  };
  auto FOLD = [&]() {
#pragma unroll
    for (int mi = 0; mi < 4; mi++)
#pragma unroll
      for (int ni = 0; ni < 2; ni++)
#pragma unroll
        for (int rr = 0; rr < 4; rr++) {
          double d = (double)acc[mi][ni][rr] * Sstep;
          float tf = (float)rint(d);
          tf = fminf(fmaxf(tf, -128.f), 127.f);
          tot[mi][ni][rr] += tf;
          acc[mi][ni][rr] = 0.f;
        }
  };

  // ---- prologue: slab(0) + B chunk (0,0) into buffer 0 ----
  STAGE_SLAB(0);
  STAGE_B(0, 0);
  int bb = 0;   // buffer holding the CURRENT compute chunk

#pragma unroll 1
  for (int g = 0; g < NG; g++) {
#pragma unroll
    for (int rc = 0; rc < 3; rc++) {
      // one barrier per chunk: drains chunk (g,rc)'s loads (B into lB[bb], plus
      // slab(g) when rc==0) and closes the WAR window for lB[bb] (its previous
      // reads ended 2 chunks ago, before the last barrier).
      __syncthreads();
      if (rc == 0 && g > 0) FOLD();       // register-only, once per group
      // ---- compute chunk (g,rc): 3 runs x 8 MFMA per wave ----
#pragma unroll
      for (int ri = 0; ri < 3; ri++) {
        short8 afr[4], bfr[2];
#pragma unroll
        for (int mi = 0; mi < 4; mi++)
          afr[mi] = *(const short8*)&sA[addrA[mi][rc * 3 + ri]];
#pragma unroll
        for (int ni = 0; ni < 2; ni++)
          bfr[ni] = *(const short8*)&lB[bb + ri * 4096 + bno[ni]];
#pragma unroll
        for (int mi = 0; mi < 4; mi++)
#pragma unroll
          for (int ni = 0; ni < 2; ni++)
            acc[mi][ni] = __builtin_amdgcn_mfma_f32_16x16x32_bf16(afr[mi], bfr[ni], acc[mi][ni], 0, 0, 0);
      }
      // ---- stage next chunk (R6/R10-proven position: after compute) ----
      if (rc < 2) {
        STAGE_B(g * GK + (rc + 1) * 96, bb ^ 12288);   // other buffer: WAR-safe
      } else if (g < 8) {
        __syncthreads();                  // all waves done reading slab(g)
        STAGE_SLAB(g + 1);                // single-buffered slab: needs the barrier
        STAGE_B((g + 1) * GK, bb ^ 12288);
      }
      bb ^= 12288;
    }
  }
  // ---- final group's ADC fold ----
#pragma unroll
  for (int mi = 0; mi < 4; mi++)
#pragma unroll
    for (int ni = 0; ni < 2; ni++)
#pragma unroll
      for (int rr = 0; rr < 4; rr++) {
        double d = (double)acc[mi][ni][rr] * Sstep;
        float tf = (float)rint(d);
        tf = fminf(fmaxf(tf, -128.f), 127.f);
        tot[mi][ni][rr] += tf;
      }

  // ---- epilogue ----
#pragma unroll
  for (int mi = 0; mi < 4; mi++)
#pragma unroll
    for (int ni = 0; ni < 2; ni++) {
      int o = n0 + wn + ni * 16 + fm;
      int p = p0 + wm + mi * 16 + fq * 4;
      float4 o4;
      o4.x = tot[mi][ni][0] * 1e-3f;
      o4.y = tot[mi][ni][1] * 1e-3f;
      o4.z = tot[mi][ni][2] * 1e-3f;
      o4.w = tot[mi][ni][3] * 1e-3f;
      *(float4*)(out + ((size_t)(b * NO + o)) * NPIX + p) = o4;
    }
}

extern "C" void kernel_launch(void* const* d_in, const int* in_sizes, int n_in,
                              void* d_out, int out_size, void* d_ws, size_t ws_size,
                              hipStream_t stream) {
  const float* x = (const float*)d_in[0];
  const float* w = (const float*)d_in[1];
  float* out = (float*)d_out;

  float* pmax = (float*)d_ws;                                // [0]=x absmax bits, [1]=w
  u16* qa = (u16*)((char*)d_ws + 8192);                      // padded acts: 18,939,904 B
  u16* wq = (u16*)((char*)d_ws + 8192 + 18939904 + 8192);    // weights: 256*2592*2 B

  hipMemsetAsync(d_ws, 0, 8, stream);                        // zero the two absmax slots

  fused_pre<<<1376, 256, 0, stream>>>((const float4*)x, (NB * NC * NH * NW) / 4,
                                      (const float4*)w, (NO * NC * KPIX) / 4,
                                      pmax, qa);
  fused_quant<<<1024 + 2592, 256, 0, stream>>>(x, w, pmax, qa, wq, out + (out_size - 1));
  gemm_adc<<<dim3(256, 2), 512, 0, stream>>>(qa, wq, pmax, out);
}